// Round 20
// baseline (866.249 us; speedup 1.0000x reference)
//
#include <hip/hip_runtime.h>
#include <hip/hip_bf16.h>

// SwinMLP block, fp32 in/out, bf16 MFMA internals.
//   1) cvt_pack32: w1/w2 -> bf16 packed 32x32-MFMA B-fragments
//   2) fused_pre: LN1 + spatial mix + residual -> x2 (d_out); LN2 -> y (bf16)
//      [R20: 4 rows/iteration, 1 barrier/row — was 2/row]
//   3) gemm32<512,2048,GELU>: z = gelu(y @ w1 + b1)
//   4) gemm32<2048,512,RES>:  d_out = x2 + z @ w2 + b2
//
// GEMM status: NINE structural variants (R12-R19: drain/ring/dbuf/read-ahead/
// B-stream/occupancy/BK/MFMA-shape/tile) all within +-8% of 370us/gemm
// (~567 TF) with no saturated pipe counter — structure-family ceiling for
// this tall-skinny shape at HIP level. GEMMs frozen at R19 (best total 863).
// R20 targets fused_pre: VALUBusy 29% + HBM 21% + 0 conflicts = stall/
// barrier-bound (4 barriers per 2 rows, 49 serial pairs). Now 4 rows per
// 4-barrier iteration + 4x load ILP per interval.

typedef __bf16 bf16x8 __attribute__((ext_vector_type(8)));
typedef float f32x16 __attribute__((ext_vector_type(16)));

constexpr int CDIM = 512;
constexpr int HID = 2048;
constexpr int MROWS = 32 * 3136;  // 100352 = 784 * 128
constexpr float LN_EPS = 1e-5f;

static __device__ __forceinline__ float gelu_tanh(float x) {
  const float u = 0.7978845608028654f * fmaf(0.044715f * x * x, x, x);
  const float e = __expf(2.0f * u);
  return 0.5f * x * (2.0f - 2.0f / (e + 1.0f));
}

static __device__ __forceinline__ void load_lds16(const void* g, void* l) {
  // 16B/lane; LDS dest = wave-uniform base + lane*16 (linear)
  __builtin_amdgcn_global_load_lds((__attribute__((address_space(1))) void*)g,
                                   (__attribute__((address_space(3))) void*)l,
                                   16, 0, 0);
}

// ---- pack fp32 w[KD][ND] -> bf16 32x32-frag blocks ----
// Block o = (g*NKT2 + t)*64 + l (16B each): n = g*32 + (l&31),
// k = t*16 + (l>>5)*8 + j, j = 0..7.
template <int KD, int ND>
__global__ __launch_bounds__(256) void cvt_pack32(
    const float* __restrict__ src, __hip_bfloat16* __restrict__ dst) {
  constexpr int NKT2 = KD / 16;
  const int o = blockIdx.x * 256 + threadIdx.x;
  const int l = o & 63;
  const int gt = o >> 6;
  const int t = gt & (NKT2 - 1), g = gt / NKT2;
  const int n = g * 32 + (l & 31);
  const int k0 = t * 16 + (l >> 5) * 8;
  __hip_bfloat16 v[8];
#pragma unroll
  for (int j = 0; j < 8; ++j)
    v[j] = __float2bfloat16(src[(size_t)(k0 + j) * ND + n]);
  *(uint4*)(dst + (size_t)o * 8) = *(const uint4*)v;
}

// ---- fused LN1 + spatial mix + residual + LN2, 4 rows / iteration ----
// Thread owns cols c0, c0+1 (same head) for all 4 rows. 4 barriers / 4 rows.
__global__ __launch_bounds__(256) void fused_pre(
    const float* __restrict__ x, const float* __restrict__ g1,
    const float* __restrict__ b1, const float* __restrict__ wsp,
    const float* __restrict__ g2, const float* __restrict__ b2,
    float* __restrict__ x2out, __hip_bfloat16* __restrict__ yout) {
  __shared__ float lnbuf[4][CDIM];
  __shared__ float red[4][4][2];  // [wave][row][stat]

  const int t = threadIdx.x;
  const int lane = t & 63;
  const int w = t >> 6;
  const int c0 = 2 * t;
  const int hd = c0 >> 5, e0 = c0 & 31;

  float wc0[32], wc1[32];
#pragma unroll
  for (int d = 0; d < 32; ++d) {
    const float2 wv = *(const float2*)&wsp[(hd * 32 + d) * 32 + e0];
    wc0[d] = wv.x;
    wc1[d] = wv.y;
  }
  const float2 g1v = *(const float2*)&g1[c0];
  const float2 b1v = *(const float2*)&b1[c0];
  const float2 g2v = *(const float2*)&g2[c0];
  const float2 b2v = *(const float2*)&b2[c0];

  for (int rq = blockIdx.x; rq < MROWS / 4; rq += gridDim.x) {
    const size_t r0 = (size_t)rq * 4;
    float2 xv[4];
#pragma unroll
    for (int r = 0; r < 4; ++r)
      xv[r] = *(const float2*)&x[(r0 + r) * CDIM + c0];

    float s[4], q[4];
#pragma unroll
    for (int r = 0; r < 4; ++r) {
      s[r] = xv[r].x + xv[r].y;
      q[r] = xv[r].x * xv[r].x + xv[r].y * xv[r].y;
    }
#pragma unroll
    for (int off = 32; off; off >>= 1)
#pragma unroll
      for (int r = 0; r < 4; ++r) {
        s[r] += __shfl_down(s[r], off);
        q[r] += __shfl_down(q[r], off);
      }
    if (lane == 0)
#pragma unroll
      for (int r = 0; r < 4; ++r) {
        red[w][r][0] = s[r];
        red[w][r][1] = q[r];
      }
    __syncthreads();  // B1
    float mu[4], rs[4];
#pragma unroll
    for (int r = 0; r < 4; ++r) {
      s[r] = red[0][r][0] + red[1][r][0] + red[2][r][0] + red[3][r][0];
      q[r] = red[0][r][1] + red[1][r][1] + red[2][r][1] + red[3][r][1];
      mu[r] = s[r] * (1.0f / CDIM);
      rs[r] = rsqrtf(q[r] * (1.0f / CDIM) - mu[r] * mu[r] + LN_EPS);
      lnbuf[r][c0] = (xv[r].x - mu[r]) * rs[r] * g1v.x + b1v.x;
      lnbuf[r][c0 + 1] = (xv[r].y - mu[r]) * rs[r] * g1v.y + b1v.y;
    }
    __syncthreads();  // B2

    float h[4][2] = {};
#pragma unroll
    for (int d = 0; d < 32; ++d) {
#pragma unroll
      for (int r = 0; r < 4; ++r) {
        const float lv = lnbuf[r][hd * 32 + d];
        h[r][0] = fmaf(lv, wc0[d], h[r][0]);
        h[r][1] = fmaf(lv, wc1[d], h[r][1]);
      }
    }
    float a[4][2];
#pragma unroll
    for (int r = 0; r < 4; ++r) {
      a[r][0] = xv[r].x + h[r][0];
      a[r][1] = xv[r].y + h[r][1];
      float2 av;
      av.x = a[r][0];
      av.y = a[r][1];
      *(float2*)&x2out[(r0 + r) * CDIM + c0] = av;
      s[r] = a[r][0] + a[r][1];
      q[r] = a[r][0] * a[r][0] + a[r][1] * a[r][1];
    }
#pragma unroll
    for (int off = 32; off; off >>= 1)
#pragma unroll
      for (int r = 0; r < 4; ++r) {
        s[r] += __shfl_down(s[r], off);
        q[r] += __shfl_down(q[r], off);
      }
    if (lane == 0)
#pragma unroll
      for (int r = 0; r < 4; ++r) {
        red[w][r][0] = s[r];
        red[w][r][1] = q[r];
      }
    __syncthreads();  // B3
#pragma unroll
    for (int r = 0; r < 4; ++r) {
      s[r] = red[0][r][0] + red[1][r][0] + red[2][r][0] + red[3][r][0];
      q[r] = red[0][r][1] + red[1][r][1] + red[2][r][1] + red[3][r][1];
      mu[r] = s[r] * (1.0f / CDIM);
      rs[r] = rsqrtf(q[r] * (1.0f / CDIM) - mu[r] * mu[r] + LN_EPS);
      __hip_bfloat162 yv;
      yv.x = __float2bfloat16((a[r][0] - mu[r]) * rs[r] * g2v.x + b2v.x);
      yv.y = __float2bfloat16((a[r][1] - mu[r]) * rs[r] * g2v.y + b2v.y);
      *(__hip_bfloat162*)&yout[(r0 + r) * CDIM + c0] = yv;
    }
    __syncthreads();  // B4 (lnbuf/red reuse)
  }
}

// ---- 128x128 tile, 4 waves, BK=32, 32x32x16 MFMA; A LDS-dbuf, B streamed ---
// (R19, frozen — best of 9 structural variants)
template <int K, int N, bool GELU>
__global__ __launch_bounds__(256, 3) void gemm32(
    const __hip_bfloat16* __restrict__ A, const char* __restrict__ Bp,
    const float* __restrict__ bias, __hip_bfloat16* __restrict__ zout,
    float* __restrict__ fout) {
  constexpr int NT = N / 128;
  constexpr int NKT2 = K / 16;  // packed-B 16-k tile count
  constexpr int NST = K / 32;   // barrier steps
  __shared__ __attribute__((aligned(16))) char smem[32768];  // 2x8KB + bounce

  const int tid = threadIdx.x;
  const int lane = tid & 63;
  const int w = tid >> 6;             // 0..3
  const int wr = w >> 1, wc = w & 1;  // wave tile 64x64

  // T1: XCD-aware bijective swizzle (grid % 8 == 0 by construction)
  const int cpx = gridDim.x >> 3;
  const int bid = (blockIdx.x & 7) * cpx + (blockIdx.x >> 3);
  const int tm = bid / NT, tn = bid - tm * NT;
  const size_t am0 = (size_t)tm * 128;
  const int bn0 = tn * 128;

  // A staging: 8KB slab = 128 rows x 32 k bf16
  const int r0 = tid >> 2, q0 = tid & 3;
  const __hip_bfloat16* aP0 = A + (am0 + r0) * K + q0 * 8;
  const __hip_bfloat16* aP1 = aP0 + (size_t)64 * K;
  const int wb = w * 1024;  // wave-uniform quarter offset

  // A-frag geometry (32x32x16): row = wr*64 + mi*32 + (lane&31);
  // byte = row*64 + kh*32 + (lane>>5)*16
  const int arow = (lane & 31);
  const int akb = (lane >> 5) * 16;
  const int abase = (wr * 64 + arow) * 64 + akb;  // + slot + mi*2048 + kh*32

  // B packed stream: n-group g = tn*4 + wc*2 + ni; frag (g*NKT2 + t16)*1024
  const char* bBase =
      Bp + ((size_t)(tn * 4 + wc * 2) * NKT2) * 1024 + lane * 16;

#define STAGE_A(so, kt)                                       \
  do {                                                        \
    load_lds16(aP0 + (kt) * 32, smem + (so) + wb);            \
    load_lds16(aP1 + (kt) * 32, smem + (so) + 4096 + wb);     \
  } while (0)

  f32x16 acc[2][2] = {};
  bf16x8 bf[2][2], bfn[2][2], af[2][2];

  // prologue: A tile0 -> slot0; B frags of step 0 (t16 = 0,1)
  STAGE_A(0, 0);
#pragma unroll
  for (int ni = 0; ni < 2; ++ni)
#pragma unroll
    for (int kh = 0; kh < 2; ++kh)
      bf[ni][kh] = *(const bf16x8*)(bBase + ((size_t)ni * NKT2 + kh) * 1024);
  __syncthreads();

  for (int t = 0; t < NST; ++t) {
    const int d = (t & 1) * 8192, dn = 8192 - d;
    // issue next step's A-stage and B-prefetch FIRST
    if (t + 1 < NST) {
      STAGE_A(dn, t + 1);
#pragma unroll
      for (int ni = 0; ni < 2; ++ni)
#pragma unroll
        for (int kh = 0; kh < 2; ++kh)
          bfn[ni][kh] = *(const bf16x8*)(bBase +
                                         ((size_t)ni * NKT2 + 2 * (t + 1) + kh) *
                                             1024);
    }

#pragma unroll
    for (int mi = 0; mi < 2; ++mi)
#pragma unroll
      for (int kh = 0; kh < 2; ++kh)
        af[mi][kh] =
            *(const bf16x8*)(smem + d + abase + mi * 2048 + kh * 32);
#pragma unroll
    for (int kh = 0; kh < 2; ++kh)
#pragma unroll
      for (int mi = 0; mi < 2; ++mi)
#pragma unroll
        for (int ni = 0; ni < 2; ++ni)
          acc[mi][ni] = __builtin_amdgcn_mfma_f32_32x32x16_bf16(
              af[mi][kh], bf[ni][kh], acc[mi][ni], 0, 0, 0);
    if (t + 1 < NST) {
#pragma unroll
      for (int ni = 0; ni < 2; ++ni)
#pragma unroll
        for (int kh = 0; kh < 2; ++kh) bf[ni][kh] = bfn[ni][kh];
    }
    __syncthreads();  // drains A-stage + B prefetch; seals slot d
  }
#undef STAGE_A

  // ---- epilogue via 32KB LDS bounce ----
  // 32x32 C/D map: col = lane&31, row = (reg&3)+8*(reg>>2)+4*(lane>>5)
  // [m74/m101-verified]
  const int ccol = lane & 31;
  const int rbase = 4 * (lane >> 5);
  char* smb = smem;

  if constexpr (GELU) {
    __hip_bfloat16* ot = (__hip_bfloat16*)smb;
#pragma unroll
    for (int ni = 0; ni < 2; ++ni) {
      const int col = wc * 64 + ni * 32 + ccol;
      const float bv = bias[bn0 + col];
#pragma unroll
      for (int mi = 0; mi < 2; ++mi)
#pragma unroll
        for (int r = 0; r < 16; ++r) {
          const int row = wr * 64 + mi * 32 + (r & 3) + 8 * (r >> 2) + rbase;
          ot[row * 128 + col] =
              __float2bfloat16(gelu_tanh(acc[mi][ni][r] + bv));
        }
    }
    __syncthreads();
#pragma unroll
    for (int it = 0; it < 8; ++it) {
      const int seg = it * 256 + tid;  // 2048 x 16B = 32KB
      const int row = seg >> 4, cs = seg & 15;
      const uint4 v = *(const uint4*)(smb + seg * 16);
      *(uint4*)&zout[(am0 + row) * N + bn0 + cs * 8] = v;
    }
  } else {
    float* ot = (float*)smb;
#pragma unroll
    for (int p = 0; p < 2; ++p) {
      if (p) __syncthreads();
      if (wr == p) {
#pragma unroll
        for (int ni = 0; ni < 2; ++ni) {
          const int col = wc * 64 + ni * 32 + ccol;
          const float bv = bias[bn0 + col];
#pragma unroll
          for (int mi = 0; mi < 2; ++mi)
#pragma unroll
            for (int r = 0; r < 16; ++r) {
              const int rl = mi * 32 + (r & 3) + 8 * (r >> 2) + rbase;
              ot[rl * 128 + col] = acc[mi][ni][r] + bv;
            }
        }
      }
      __syncthreads();
#pragma unroll
      for (int it = 0; it < 8; ++it) {
        const int seg = it * 256 + tid;  // 2048 x 16B = 32KB
        const int row = seg >> 5, cs = seg & 31;
        const float4 lv = *(const float4*)(smb + seg * 16);
        float* gp = &fout[(am0 + p * 64 + row) * N + bn0 + cs * 4];
        float4 o = *(const float4*)gp;
        o.x += lv.x;
        o.y += lv.y;
        o.z += lv.z;
        o.w += lv.w;
        *(float4*)gp = o;
      }
    }
  }
}

extern "C" void kernel_launch(void* const* d_in, const int* in_sizes, int n_in,
                              void* d_out, int out_size, void* d_ws,
                              size_t ws_size, hipStream_t stream) {
  const float* x = (const float*)d_in[0];
  const float* n1g = (const float*)d_in[1];
  const float* n1b = (const float*)d_in[2];
  const float* wsp = (const float*)d_in[3];
  const float* n2g = (const float*)d_in[4];
  const float* n2b = (const float*)d_in[5];
  const float* w1 = (const float*)d_in[6];
  const float* b1 = (const float*)d_in[7];
  const float* w2 = (const float*)d_in[8];
  const float* b2 = (const float*)d_in[9];
  float* out = (float*)d_out;

  // ws (bf16): y[M*512] row-major | z[M*2048] row-major | w1p | w2p (packed32)
  __hip_bfloat16* ybuf = (__hip_bfloat16*)d_ws;
  __hip_bfloat16* zbuf = ybuf + (size_t)MROWS * CDIM;
  __hip_bfloat16* w1p = zbuf + (size_t)MROWS * HID;
  __hip_bfloat16* w2p = w1p + (size_t)CDIM * HID;

  cvt_pack32<CDIM, HID><<<512, 256, 0, stream>>>(w1, w1p);  // w1[512][2048]
  cvt_pack32<HID, CDIM><<<512, 256, 0, stream>>>(w2, w2p);  // w2[2048][512]
  fused_pre<<<2048, 256, 0, stream>>>(x, n1g, n1b, wsp, n2g, n2b, out, ybuf);
  // grids: 784*16 = 12544 and 784*4 = 3136, both % 8 == 0
  gemm32<CDIM, HID, true><<<(MROWS / 128) * (HID / 128), 256, 0, stream>>>(
      ybuf, (const char*)w1p, b1, zbuf, nullptr);
  gemm32<HID, CDIM, false><<<(MROWS / 128) * (CDIM / 128), 256, 0, stream>>>(
      zbuf, (const char*)w2p, b2, nullptr, out);
}

// Round 21
// 825.109 us; speedup vs baseline: 1.0499x; 1.0499x over previous
//
#include <hip/hip_runtime.h>
#include <hip/hip_bf16.h>

// SwinMLP block, fp32 in/out, bf16 MFMA internals.
//   1) cvt_pack32: w1/w2 -> bf16 packed 32x32-MFMA B-fragments
//   2) fused_pre: LN1 + spatial mix + residual -> x2 (d_out); LN2 -> y PACKED32
//   3) gemm32p<512,2048,GELU>: z = gelu(y @ w1 + b1) -> z PACKED32
//   4) gemm32p<2048,512,RES>:  d_out = x2 + z @ w2 + b2
//
// R21: PACKED-A end-to-end. R19's A-frag ds_read at 64B row stride = 32 lanes
// on 8 banks (~4x replay; SQ_LDS_BANK_CONFLICT 3.85e7 — R8's "swizzle null"
// verdict was from polluted totals, reopened). Fix without swizzle: store
// y and z in MFMA-fragment-packed32 layout (R16-proven): A-staging = linear
// 1KB-block copies; A-frag read byte = block*1024 + lane*16 (packed32
// l=(row&31)+32*kg == lane) -> lane-linear, conflict-free. B-stream, MFMA
// loop, sync, epilogues otherwise identical to R19 (best passing, 863us).

typedef __bf16 bf16x8 __attribute__((ext_vector_type(8)));
typedef float f32x16 __attribute__((ext_vector_type(16)));

constexpr int CDIM = 512;
constexpr int HID = 2048;
constexpr int MROWS = 32 * 3136;  // 100352 = 784 * 128
constexpr float LN_EPS = 1e-5f;

static __device__ __forceinline__ float gelu_tanh(float x) {
  const float u = 0.7978845608028654f * fmaf(0.044715f * x * x, x, x);
  const float e = __expf(2.0f * u);
  return 0.5f * x * (2.0f - 2.0f / (e + 1.0f));
}

static __device__ __forceinline__ void load_lds16(const void* g, void* l) {
  // 16B/lane; LDS dest = wave-uniform base (+ HW lane*16)
  __builtin_amdgcn_global_load_lds((__attribute__((address_space(1))) void*)g,
                                   (__attribute__((address_space(3))) void*)l,
                                   16, 0, 0);
}

// ---- pack fp32 w[KD][ND] -> bf16 32x32-frag blocks (B-operand) ----
// Block o = (g*NKT2 + t)*64 + l (16B each): n = g*32 + (l&31),
// k = t*16 + (l>>5)*8 + j, j = 0..7.
template <int KD, int ND>
__global__ __launch_bounds__(256) void cvt_pack32(
    const float* __restrict__ src, __hip_bfloat16* __restrict__ dst) {
  constexpr int NKT2 = KD / 16;
  const int o = blockIdx.x * 256 + threadIdx.x;
  const int l = o & 63;
  const int gt = o >> 6;
  const int t = gt & (NKT2 - 1), g = gt / NKT2;
  const int n = g * 32 + (l & 31);
  const int k0 = t * 16 + (l >> 5) * 8;
  __hip_bfloat16 v[8];
#pragma unroll
  for (int j = 0; j < 8; ++j)
    v[j] = __float2bfloat16(src[(size_t)(k0 + j) * ND + n]);
  *(uint4*)(dst + (size_t)o * 8) = *(const uint4*)v;
}

// ---- fused LN1 + spatial mix + residual + LN2, 4 rows/iter; y out PACKED32 -
// packed32 A-layout: elem(row,k) -> block ((row>>5)*(CDIM/16) + (k>>4)),
// l = (row&31) + 32*((k>>3)&1), j = k&7; elem off = block*512 + l*8 + j.
__global__ __launch_bounds__(256) void fused_pre(
    const float* __restrict__ x, const float* __restrict__ g1,
    const float* __restrict__ b1, const float* __restrict__ wsp,
    const float* __restrict__ g2, const float* __restrict__ b2,
    float* __restrict__ x2out, __hip_bfloat16* __restrict__ yout) {
  __shared__ float lnbuf[4][CDIM];
  __shared__ float red[4][4][2];  // [wave][row][stat]

  const int t = threadIdx.x;
  const int lane = t & 63;
  const int w = t >> 6;
  const int c0 = 2 * t;
  const int hd = c0 >> 5, e0 = c0 & 31;
  // packed32 col-constant part: t-block + l-kpart*8 + j
  const int ypc32 = (c0 >> 4) * 512 + ((c0 >> 3) & 1) * 256 + (c0 & 7);

  float wc0[32], wc1[32];
#pragma unroll
  for (int d = 0; d < 32; ++d) {
    const float2 wv = *(const float2*)&wsp[(hd * 32 + d) * 32 + e0];
    wc0[d] = wv.x;
    wc1[d] = wv.y;
  }
  const float2 g1v = *(const float2*)&g1[c0];
  const float2 b1v = *(const float2*)&b1[c0];
  const float2 g2v = *(const float2*)&g2[c0];
  const float2 b2v = *(const float2*)&b2[c0];

  for (int rq = blockIdx.x; rq < MROWS / 4; rq += gridDim.x) {
    const size_t r0 = (size_t)rq * 4;
    float2 xv[4];
#pragma unroll
    for (int r = 0; r < 4; ++r)
      xv[r] = *(const float2*)&x[(r0 + r) * CDIM + c0];

    float s[4], q[4];
#pragma unroll
    for (int r = 0; r < 4; ++r) {
      s[r] = xv[r].x + xv[r].y;
      q[r] = xv[r].x * xv[r].x + xv[r].y * xv[r].y;
    }
#pragma unroll
    for (int off = 32; off; off >>= 1)
#pragma unroll
      for (int r = 0; r < 4; ++r) {
        s[r] += __shfl_down(s[r], off);
        q[r] += __shfl_down(q[r], off);
      }
    if (lane == 0)
#pragma unroll
      for (int r = 0; r < 4; ++r) {
        red[w][r][0] = s[r];
        red[w][r][1] = q[r];
      }
    __syncthreads();  // B1
    float mu[4], rs[4];
#pragma unroll
    for (int r = 0; r < 4; ++r) {
      s[r] = red[0][r][0] + red[1][r][0] + red[2][r][0] + red[3][r][0];
      q[r] = red[0][r][1] + red[1][r][1] + red[2][r][1] + red[3][r][1];
      mu[r] = s[r] * (1.0f / CDIM);
      rs[r] = rsqrtf(q[r] * (1.0f / CDIM) - mu[r] * mu[r] + LN_EPS);
      lnbuf[r][c0] = (xv[r].x - mu[r]) * rs[r] * g1v.x + b1v.x;
      lnbuf[r][c0 + 1] = (xv[r].y - mu[r]) * rs[r] * g1v.y + b1v.y;
    }
    __syncthreads();  // B2

    float h[4][2] = {};
#pragma unroll
    for (int d = 0; d < 32; ++d) {
#pragma unroll
      for (int r = 0; r < 4; ++r) {
        const float lv = lnbuf[r][hd * 32 + d];
        h[r][0] = fmaf(lv, wc0[d], h[r][0]);
        h[r][1] = fmaf(lv, wc1[d], h[r][1]);
      }
    }
    float a[4][2];
#pragma unroll
    for (int r = 0; r < 4; ++r) {
      a[r][0] = xv[r].x + h[r][0];
      a[r][1] = xv[r].y + h[r][1];
      float2 av;
      av.x = a[r][0];
      av.y = a[r][1];
      *(float2*)&x2out[(r0 + r) * CDIM + c0] = av;
      s[r] = a[r][0] + a[r][1];
      q[r] = a[r][0] * a[r][0] + a[r][1] * a[r][1];
    }
#pragma unroll
    for (int off = 32; off; off >>= 1)
#pragma unroll
      for (int r = 0; r < 4; ++r) {
        s[r] += __shfl_down(s[r], off);
        q[r] += __shfl_down(q[r], off);
      }
    if (lane == 0)
#pragma unroll
      for (int r = 0; r < 4; ++r) {
        red[w][r][0] = s[r];
        red[w][r][1] = q[r];
      }
    __syncthreads();  // B3
#pragma unroll
    for (int r = 0; r < 4; ++r) {
      s[r] = red[0][r][0] + red[1][r][0] + red[2][r][0] + red[3][r][0];
      q[r] = red[0][r][1] + red[1][r][1] + red[2][r][1] + red[3][r][1];
      mu[r] = s[r] * (1.0f / CDIM);
      rs[r] = rsqrtf(q[r] * (1.0f / CDIM) - mu[r] * mu[r] + LN_EPS);
      __hip_bfloat162 yv;
      yv.x = __float2bfloat16((a[r][0] - mu[r]) * rs[r] * g2v.x + b2v.x);
      yv.y = __float2bfloat16((a[r][1] - mu[r]) * rs[r] * g2v.y + b2v.y);
      const size_t rr = r0 + r;
      *(__hip_bfloat162*)&yout[(rr >> 5) * 16384 + (rr & 31) * 8 + ypc32] = yv;
    }
    __syncthreads();  // B4 (lnbuf/red reuse)
  }
}

// ---- 128x128 tile, 4 waves, BK=32, 32x32x16; A PACKED (LDS dbuf, linear),
// B packed global-stream. A-frag read = block*1024 + lane*16: conflict-free.
// GELU: z out PACKED32. else: fp32 RMW row-major (R19-proven).
template <int K, int N, bool GELU>
__global__ __launch_bounds__(256, 3) void gemm32p(
    const char* __restrict__ Ap, const char* __restrict__ Bp,
    const float* __restrict__ bias, char* __restrict__ zp,
    float* __restrict__ fout) {
  constexpr int NT = N / 128;
  constexpr int NKT2A = K / 16;  // packed-A t-block count
  constexpr int NKT2 = K / 16;   // packed-B t-block count
  constexpr int NST = K / 32;    // barrier steps
  __shared__ __attribute__((aligned(16))) char smem[32768];  // 2x8KB + bounce

  const int tid = threadIdx.x;
  const int lane = tid & 63;
  const int w = tid >> 6;             // 0..3
  const int wr = w >> 1, wc = w & 1;  // wave tile 64x64

  // T1: XCD-aware bijective swizzle (grid % 8 == 0 by construction)
  const int cpx = gridDim.x >> 3;
  const int bid = (blockIdx.x & 7) * cpx + (blockIdx.x >> 3);
  const int tm = bid / NT, tn = bid - tm * NT;
  const size_t am0 = (size_t)tm * 128;
  const int bn0 = tn * 128;

  // A staging (packed): per step t, 8 blocks (g'=0..3, th=0..1) = 8KB.
  // Thread stages segs tid and tid+256: seg s -> g'=s>>7, th=(s>>6)&1, l=lane.
  const size_t aBlk0 = ((size_t)(tm * 4 + (tid >> 7)) * NKT2A + ((tid >> 6) & 1));
  const size_t aBlk1 = aBlk0 + (size_t)2 * NKT2A;  // g' + 2
  const char* aP0 = Ap + aBlk0 * 1024 + lane * 16;
  const char* aP1 = Ap + aBlk1 * 1024 + lane * 16;
  const int ldsA0 = (tid >> 6) * 1024;         // wave-uniform dest (s0)
  const int ldsA1 = 4096 + (tid >> 6) * 1024;  // (s1)

  // B packed stream: n-group g = tn*4 + wc*2 + ni; frag (g*NKT2 + t16)*1024
  const char* bBase =
      Bp + ((size_t)(tn * 4 + wc * 2) * NKT2) * 1024 + lane * 16;

#define STAGE_A(so, kt)                                   \
  do {                                                    \
    load_lds16(aP0 + (size_t)(kt) * 2048, smem + (so) + ldsA0); \
    load_lds16(aP1 + (size_t)(kt) * 2048, smem + (so) + ldsA1); \
  } while (0)

  f32x16 acc[2][2] = {};
  bf16x8 bf[2][2], bfn[2][2], af[2][2];

  // prologue
  STAGE_A(0, 0);
#pragma unroll
  for (int ni = 0; ni < 2; ++ni)
#pragma unroll
    for (int kh = 0; kh < 2; ++kh)
      bf[ni][kh] = *(const bf16x8*)(bBase + ((size_t)ni * NKT2 + kh) * 1024);
  __syncthreads();

  for (int t = 0; t < NST; ++t) {
    const int d = (t & 1) * 8192, dn = 8192 - d;
    if (t + 1 < NST) {
      STAGE_A(dn, t + 1);
#pragma unroll
      for (int ni = 0; ni < 2; ++ni)
#pragma unroll
        for (int kh = 0; kh < 2; ++kh)
          bfn[ni][kh] =
              *(const bf16x8*)(bBase +
                               ((size_t)ni * NKT2 + 2 * (t + 1) + kh) * 1024);
    }

    // A-frag reads: LINEAR (block = (wr*2+mi)*2 + kh), conflict-free
#pragma unroll
    for (int mi = 0; mi < 2; ++mi)
#pragma unroll
      for (int kh = 0; kh < 2; ++kh)
        af[mi][kh] = *(const bf16x8*)(smem + d + ((wr * 2 + mi) * 2 + kh) * 1024 +
                                      lane * 16);
#pragma unroll
    for (int kh = 0; kh < 2; ++kh)
#pragma unroll
      for (int mi = 0; mi < 2; ++mi)
#pragma unroll
        for (int ni = 0; ni < 2; ++ni)
          acc[mi][ni] = __builtin_amdgcn_mfma_f32_32x32x16_bf16(
              af[mi][kh], bf[ni][kh], acc[mi][ni], 0, 0, 0);
    if (t + 1 < NST) {
#pragma unroll
      for (int ni = 0; ni < 2; ++ni)
#pragma unroll
        for (int kh = 0; kh < 2; ++kh) bf[ni][kh] = bfn[ni][kh];
    }
    __syncthreads();  // drains A-stage + B prefetch; seals slot d
  }
#undef STAGE_A

  // ---- epilogue via 32KB LDS bounce ----
  // 32x32 C/D map: col = lane&31, row = (reg&3)+8*(reg>>2)+4*(lane>>5)
  const int ccol = lane & 31;
  const int rbase = 4 * (lane >> 5);
  char* smb = smem;

  if constexpr (GELU) {
    // z out PACKED32: local blk = (row>>5)*8 + (col>>4);
    // l = (row&31) + 32*((col>>3)&1); j = col&7
#pragma unroll
    for (int ni = 0; ni < 2; ++ni) {
      const int col = wc * 64 + ni * 32 + ccol;
      const float bv = bias[bn0 + col];
      const int cpart = (col >> 4) * 1024 + ((col >> 3) & 1) * 512 + (col & 7) * 2;
#pragma unroll
      for (int mi = 0; mi < 2; ++mi)
#pragma unroll
        for (int r = 0; r < 16; ++r) {
          const int row = wr * 64 + mi * 32 + (r & 3) + 8 * (r >> 2) + rbase;
          *(__hip_bfloat16*)(smb + (row >> 5) * 8192 + (row & 31) * 16 + cpart) =
              __float2bfloat16(gelu_tanh(acc[mi][ni][r] + bv));
        }
    }
    __syncthreads();
    // coalesced out: 32 blocks x 1KB; global blk id =
    // (am0/32 + (blk>>3)) * (N/16) + bn0/16 + (blk&7)
#pragma unroll
    for (int it = 0; it < 8; ++it) {
      const int seg = it * 256 + tid;  // 2048 x 16B = 32KB
      const int blk = seg >> 6, l = seg & 63;
      const size_t gb =
          ((size_t)(am0 >> 5) + (blk >> 3)) * (N / 16) + (bn0 >> 4) + (blk & 7);
      *(uint4*)(zp + gb * 1024 + l * 16) = *(const uint4*)(smb + seg * 16);
    }
  } else {
    float* ot = (float*)smb;
#pragma unroll
    for (int p = 0; p < 2; ++p) {
      if (p) __syncthreads();
      if (wr == p) {
#pragma unroll
        for (int ni = 0; ni < 2; ++ni) {
          const int col = wc * 64 + ni * 32 + ccol;
          const float bv = bias[bn0 + col];
#pragma unroll
          for (int mi = 0; mi < 2; ++mi)
#pragma unroll
            for (int r = 0; r < 16; ++r) {
              const int rl = mi * 32 + (r & 3) + 8 * (r >> 2) + rbase;
              ot[rl * 128 + col] = acc[mi][ni][r] + bv;
            }
        }
      }
      __syncthreads();
#pragma unroll
      for (int it = 0; it < 8; ++it) {
        const int seg = it * 256 + tid;  // 2048 x 16B = 32KB
        const int row = seg >> 5, cs = seg & 31;
        const float4 lv = *(const float4*)(smb + seg * 16);
        float* gp = &fout[(am0 + p * 64 + row) * N + bn0 + cs * 4];
        float4 o = *(const float4*)gp;
        o.x += lv.x;
        o.y += lv.y;
        o.z += lv.z;
        o.w += lv.w;
        *(float4*)gp = o;
      }
    }
  }
}

extern "C" void kernel_launch(void* const* d_in, const int* in_sizes, int n_in,
                              void* d_out, int out_size, void* d_ws,
                              size_t ws_size, hipStream_t stream) {
  const float* x = (const float*)d_in[0];
  const float* n1g = (const float*)d_in[1];
  const float* n1b = (const float*)d_in[2];
  const float* wsp = (const float*)d_in[3];
  const float* n2g = (const float*)d_in[4];
  const float* n2b = (const float*)d_in[5];
  const float* w1 = (const float*)d_in[6];
  const float* b1 = (const float*)d_in[7];
  const float* w2 = (const float*)d_in[8];
  const float* b2 = (const float*)d_in[9];
  float* out = (float*)d_out;

  // ws (bf16): y packed32 [M*512] | z packed32 [M*2048] | w1p | w2p (packed32)
  __hip_bfloat16* ybuf = (__hip_bfloat16*)d_ws;
  __hip_bfloat16* zbuf = ybuf + (size_t)MROWS * CDIM;
  __hip_bfloat16* w1p = zbuf + (size_t)MROWS * HID;
  __hip_bfloat16* w2p = w1p + (size_t)CDIM * HID;

  cvt_pack32<CDIM, HID><<<512, 256, 0, stream>>>(w1, w1p);  // w1[512][2048]
  cvt_pack32<HID, CDIM><<<512, 256, 0, stream>>>(w2, w2p);  // w2[2048][512]
  fused_pre<<<2048, 256, 0, stream>>>(x, n1g, n1b, wsp, n2g, n2b, out, ybuf);
  // grids: 784*16 = 12544 and 784*4 = 3136, both % 8 == 0
  gemm32p<CDIM, HID, true><<<(MROWS / 128) * (HID / 128), 256, 0, stream>>>(
      (const char*)ybuf, (const char*)w1p, b1, (char*)zbuf, nullptr);
  gemm32p<HID, CDIM, false><<<(MROWS / 128) * (CDIM / 128), 256, 0, stream>>>(
      (const char*)zbuf, (const char*)w2p, b2, nullptr, out);
}